// Round 7
// baseline (143.739 us; speedup 1.0000x reference)
//
#include <hip/hip_runtime.h>
#include <stdint.h>

#define BB 8
#define CC 256
#define NN 4096
#define KK 16
#define NT 16              // n-tile per fused block

typedef float f32x4 __attribute__((ext_vector_type(4)));
typedef short bf16x8 __attribute__((ext_vector_type(8)));
typedef int   i32x4 __attribute__((ext_vector_type(4)));
typedef unsigned int u32x2 __attribute__((ext_vector_type(2)));
typedef unsigned int u32x4 __attribute__((ext_vector_type(4)));

__device__ __forceinline__ ushort f2bf(float f) {
  union { float f; uint32_t u; } v; v.f = f;
  uint32_t r = v.u + 0x7FFFu + ((v.u >> 16) & 1u);   // RNE
  return (ushort)(r >> 16);
}
__device__ __forceinline__ float asf(uint32_t u) {
  union { uint32_t u; float f; } v; v.u = u; return v.f;
}

// K0 combined prep:
//  blocks [0,2048): x[b][c][n] f32 -> xT[b][n][c] bf16, b = bid&7 (XCD b owns
//                   batch b's slab; x reads nontemporal). At HBM roofline
//                   (134 MB f32 read), ~22 us — leave alone.
//  blocks [2048,2112): W[o][c] f32 -> Wfrag[kc][o][ks] bf16 (kc=c/32, ks=c%32)
__global__ __launch_bounds__(256) void k_prep(
    const float* __restrict__ x, const float* __restrict__ W,
    ushort* __restrict__ xT, ushort* __restrict__ Wfrag)
{
  const int bid = blockIdx.x;
  const int t   = threadIdx.x;
  if (bid >= 2048) {                       // W conversion
    const int wb = bid - 2048;
    const int o  = wb * 4 + (t >> 6);
    const int k0 = (t & 63) * 4;
    f32x4 v = __builtin_nontemporal_load((const f32x4*)(W + (size_t)o * CC + k0));
    ushort4 h;
    h.x = f2bf(v.x); h.y = f2bf(v.y); h.z = f2bf(v.z); h.w = f2bf(v.w);
    const int kc = k0 >> 5, ks = k0 & 31;
    *(ushort4*)(Wfrag + ((size_t)(kc * CC + o)) * 32 + ks) = h;
    return;
  }
  __shared__ float tile[64][68];
  const int b    = bid & 7;                // XCD affinity (round-robin i%8)
  const int tl   = bid >> 3;               // 256 tiles per batch
  const int c0   = (tl & 3) * 64;
  const int n0   = (tl >> 2) * 64;
  {
    const int r  = t >> 2;
    const int cs = (t & 3) * 16;
    const float* xp = x + ((size_t)b * CC + c0 + r) * NN + n0 + cs;
    #pragma unroll
    for (int i = 0; i < 4; ++i) {
      f32x4 v = __builtin_nontemporal_load((const f32x4*)(xp + i * 4));
      *(f32x4*)&tile[r][cs + i * 4] = v;
    }
  }
  __syncthreads();
  const int nl = t >> 2;
  const int cl = (t & 3) * 16;
  union { ushort s[16]; uint4 q[2]; } pk;
  #pragma unroll
  for (int i = 0; i < 16; ++i) pk.s[i] = f2bf(tile[cl + i][nl]);
  uint4* dst = (uint4*)(xT + ((size_t)b * NN + n0 + nl) * CC + c0 + cl);
  dst[0] = pk.q[0];
  dst[1] = pk.q[1];
}

// K1 fused: gather+GIN update into LDS tile, then MFMA GEMM + bias + ReLU.
// blockIdx.x = tile*8 + b  (b = bid&7 -> same XCD that produced batch b's xT)
// Phase 1 is row-per-wave: 64 lanes cover one n-row's 256 channels (4 ch/lane,
// dwordx2). Neighbor indices are wave-uniform -> readfirstlane -> SGPR base ->
// saddr-form loads with zero per-load VALU address math.
__global__ __launch_bounds__(256) void k_fused(
    const ushort* __restrict__ xT, const int* __restrict__ edge0,
    const float* __restrict__ eps, const ushort* __restrict__ Wfrag,
    const float* __restrict__ bias, float* __restrict__ out)
{
  __shared__ ushort hLds[NT][264];         // 528B row stride
  const int bid = blockIdx.x;
  const int b   = bid & 7;
  const int n0  = (bid >> 3) * NT;
  const int t    = threadIdx.x;
  const int wave = t >> 6, lane = t & 63;
  const float epsv = 1.0f + eps[0];
  const ushort* xb = xT + (size_t)b * NN * CC;
  const int c4 = lane * 4;                 // channels [c4, c4+4) per lane

  #pragma unroll
  for (int i = 0; i < NT / 4; ++i) {
    const int nl = wave * (NT / 4) + i;
    const int n  = n0 + nl;
    const i32x4* epv = (const i32x4*)(edge0 + ((size_t)b * NN + n) * KK);
    i32x4 e0 = __builtin_nontemporal_load(epv + 0);
    i32x4 e1 = __builtin_nontemporal_load(epv + 1);
    i32x4 e2 = __builtin_nontemporal_load(epv + 2);
    i32x4 e3 = __builtin_nontemporal_load(epv + 3);
    u32x2 sv = *(const u32x2*)(xb + (n << 8) + c4);

    const int js[16] = {e0.x, e0.y, e0.z, e0.w, e1.x, e1.y, e1.z, e1.w,
                        e2.x, e2.y, e2.z, e2.w, e3.x, e3.y, e3.z, e3.w};
    f32x4 acc = (f32x4){0.f, 0.f, 0.f, 0.f};
    #pragma unroll
    for (int k = 0; k < KK; ++k) {
      const int jr = __builtin_amdgcn_readfirstlane(js[k]);  // wave-uniform
      const ushort* rp = xb + ((size_t)jr << 8);             // SGPR base
      u32x2 g = *(const u32x2*)(rp + c4);                    // saddr + voffset
      acc += (f32x4){asf(g.x << 16), asf(g.x & 0xffff0000u),
                     asf(g.y << 16), asf(g.y & 0xffff0000u)};
    }
    acc += (f32x4){asf(sv.x << 16), asf(sv.x & 0xffff0000u),
                   asf(sv.y << 16), asf(sv.y & 0xffff0000u)} * epsv;

    uint2 pk;
    pk.x = (uint32_t)f2bf(acc[0]) | ((uint32_t)f2bf(acc[1]) << 16);
    pk.y = (uint32_t)f2bf(acc[2]) | ((uint32_t)f2bf(acc[3]) << 16);
    *(uint2*)&hLds[nl][c4] = pk;
  }
  __syncthreads();

  // Phase 2: GEMM. Wave w computes o in [w*64, w*64+64) x NT(=16) n.
  f32x4 acc2[4];
  #pragma unroll
  for (int m = 0; m < 4; ++m) acc2[m] = (f32x4){0.f, 0.f, 0.f, 0.f};

  const int lrow = lane & 15;
  const int kgrp = lane >> 4;
  const int o0   = wave * 64;

  #pragma unroll
  for (int kc = 0; kc < 8; ++kc) {
    const int cs = kgrp * 8;
    bf16x8 bfr = *(const bf16x8*)&hLds[lrow][kc * 32 + cs];
    bf16x8 afr[4];
    #pragma unroll
    for (int m = 0; m < 4; ++m) {
      const uint32_t aoff = (uint32_t)(kc * CC + o0 + m * 16 + lrow) * 32 + cs;
      afr[m] = *(const bf16x8*)(Wfrag + aoff);
    }
    #pragma unroll
    for (int m = 0; m < 4; ++m)
      acc2[m] = __builtin_amdgcn_mfma_f32_16x16x32_bf16(
          afr[m], bfr, acc2[m], 0, 0, 0);
  }

  // Epilogue: D col=lane&15 (n), row=(lane>>4)*4+r (o-local); bias + relu.
  const int n = n0 + lrow;
  #pragma unroll
  for (int m = 0; m < 4; ++m) {
    const f32x4 bv4 = *(const f32x4*)(bias + o0 + m * 16 + kgrp * 4);
    #pragma unroll
    for (int r = 0; r < 4; ++r) {
      const int o = o0 + m * 16 + kgrp * 4 + r;
      float v = acc2[m][r] + bv4[r];
      v = v > 0.f ? v : 0.f;
      __builtin_nontemporal_store(v, &out[((size_t)b * CC + o) * NN + n]);
    }
  }
}

extern "C" void kernel_launch(void* const* d_in, const int* in_sizes, int n_in,
                              void* d_out, int out_size, void* d_ws, size_t ws_size,
                              hipStream_t stream) {
  const float* x    = (const float*)d_in[0];
  const int*   edge = (const int*)d_in[1];   // [2][B][N][K] int32, plane 0 used
  const float* eps  = (const float*)d_in[2];
  const float* W    = (const float*)d_in[3];
  const float* bias = (const float*)d_in[4];
  float* out = (float*)d_out;

  ushort* xT    = (ushort*)d_ws;                         // [B][N][C] bf16, 16.8 MB
  ushort* Wfrag = xT + (size_t)BB * NN * CC;             // [8][C][32] bf16, 128 KB

  k_prep<<<2048 + 64, 256, 0, stream>>>(x, W, xT, Wfrag);

  k_fused<<<BB * (NN / NT), 256, 0, stream>>>(xT, edge, eps, Wfrag, bias, out);
}

// Round 8
// 137.993 us; speedup vs baseline: 1.0416x; 1.0416x over previous
//
#include <hip/hip_runtime.h>
#include <stdint.h>

#define BB 8
#define CC 256
#define NN 4096
#define KK 16

typedef float f32x4 __attribute__((ext_vector_type(4)));
typedef short bf16x8 __attribute__((ext_vector_type(8)));
typedef int   i32x4 __attribute__((ext_vector_type(4)));
typedef unsigned int u32x2 __attribute__((ext_vector_type(2)));

__device__ __forceinline__ ushort f2bf(float f) {
  union { float f; uint32_t u; } v; v.f = f;
  uint32_t r = v.u + 0x7FFFu + ((v.u >> 16) & 1u);   // RNE
  return (ushort)(r >> 16);
}
__device__ __forceinline__ float asf(uint32_t u) {
  union { uint32_t u; float f; } v; v.u = u; return v.f;
}

// K0 combined prep:
//  blocks [0,2048): x[b][c][n] f32 -> xT[b][n][c] bf16, b = bid&7 (XCD b owns
//                   batch b's slab; x reads nontemporal). ~24 us at HBM floor.
//  blocks [2048,2112): W[o][c] f32 -> Wfrag[kc][o][ks] bf16 (kc=c/32, ks=c%32)
__global__ __launch_bounds__(256) void k_prep(
    const float* __restrict__ x, const float* __restrict__ W,
    ushort* __restrict__ xT, ushort* __restrict__ Wfrag)
{
  const int bid = blockIdx.x;
  const int t   = threadIdx.x;
  if (bid >= 2048) {                       // W conversion
    const int wb = bid - 2048;
    const int o  = wb * 4 + (t >> 6);
    const int k0 = (t & 63) * 4;
    f32x4 v = __builtin_nontemporal_load((const f32x4*)(W + (size_t)o * CC + k0));
    ushort4 h;
    h.x = f2bf(v.x); h.y = f2bf(v.y); h.z = f2bf(v.z); h.w = f2bf(v.w);
    const int kc = k0 >> 5, ks = k0 & 31;
    *(ushort4*)(Wfrag + ((size_t)(kc * CC + o)) * 32 + ks) = h;
    return;
  }
  __shared__ float tile[64][68];
  const int b    = bid & 7;                // XCD affinity (round-robin i%8)
  const int tl   = bid >> 3;               // 256 tiles per batch
  const int c0   = (tl & 3) * 64;
  const int n0   = (tl >> 2) * 64;
  {
    const int r  = t >> 2;
    const int cs = (t & 3) * 16;
    const float* xp = x + ((size_t)b * CC + c0 + r) * NN + n0 + cs;
    #pragma unroll
    for (int i = 0; i < 4; ++i) {
      f32x4 v = __builtin_nontemporal_load((const f32x4*)(xp + i * 4));
      *(f32x4*)&tile[r][cs + i * 4] = v;
    }
  }
  __syncthreads();
  const int nl = t >> 2;
  const int cl = (t & 3) * 16;
  union { ushort s[16]; uint4 q[2]; } pk;
  #pragma unroll
  for (int i = 0; i < 16; ++i) pk.s[i] = f2bf(tile[cl + i][nl]);
  uint4* dst = (uint4*)(xT + ((size_t)b * NN + n0 + nl) * CC + c0 + cl);
  dst[0] = pk.q[0];
  dst[1] = pk.q[1];
}

// K1: standalone gather + GIN update -> hT[b][n][c] bf16.
// Row-per-wave, saddr gathers, NO barriers / LDS / MFMA: rows are independent
// so the scheduler keeps many loads in flight. Normal stores keep hT in the
// producing XCD's L2 (b = bid&7 affinity, same as consumer k_gemm).
__global__ __launch_bounds__(256) void k_gather(
    const ushort* __restrict__ xT, const int* __restrict__ edge0,
    const float* __restrict__ eps, ushort* __restrict__ hT)
{
  const int bid = blockIdx.x;              // 2048 blocks
  const int b   = bid & 7;
  const int n0  = (bid >> 3) * 16;
  const int wave = threadIdx.x >> 6, lane = threadIdx.x & 63;
  const float epsv = 1.0f + eps[0];
  const ushort* xb = xT + (size_t)b * NN * CC;
  ushort*       hb = hT + (size_t)b * NN * CC;
  const int c4 = lane * 4;                 // channels [c4, c4+4) per lane

  #pragma unroll
  for (int i = 0; i < 4; ++i) {
    const int n = n0 + wave * 4 + i;
    const i32x4* epv = (const i32x4*)(edge0 + ((size_t)b * NN + n) * KK);
    i32x4 e0 = __builtin_nontemporal_load(epv + 0);
    i32x4 e1 = __builtin_nontemporal_load(epv + 1);
    i32x4 e2 = __builtin_nontemporal_load(epv + 2);
    i32x4 e3 = __builtin_nontemporal_load(epv + 3);
    u32x2 sv = *(const u32x2*)(xb + (n << 8) + c4);

    const int js[16] = {e0.x, e0.y, e0.z, e0.w, e1.x, e1.y, e1.z, e1.w,
                        e2.x, e2.y, e2.z, e2.w, e3.x, e3.y, e3.z, e3.w};
    f32x4 acc = (f32x4){0.f, 0.f, 0.f, 0.f};
    #pragma unroll
    for (int k = 0; k < KK; ++k) {
      const int jr = __builtin_amdgcn_readfirstlane(js[k]);  // wave-uniform
      const ushort* rp = xb + ((size_t)jr << 8);             // SGPR base
      u32x2 g = *(const u32x2*)(rp + c4);                    // saddr + voffset
      acc += (f32x4){asf(g.x << 16), asf(g.x & 0xffff0000u),
                     asf(g.y << 16), asf(g.y & 0xffff0000u)};
    }
    acc += (f32x4){asf(sv.x << 16), asf(sv.x & 0xffff0000u),
                   asf(sv.y << 16), asf(sv.y & 0xffff0000u)} * epsv;

    uint2 pk;
    pk.x = (uint32_t)f2bf(acc[0]) | ((uint32_t)f2bf(acc[1]) << 16);
    pk.y = (uint32_t)f2bf(acc[2]) | ((uint32_t)f2bf(acc[3]) << 16);
    *(uint2*)(hb + (n << 8) + c4) = pk;    // normal store: full lines, L2-kept
  }
}

// K2: out[b][o][n] = relu(sum_c W[o][c]*hT[b][n][c] + b[o]) via MFMA.
// 64-n x 256-o tile per block; hT staged to LDS coalesced; plain out stores
// (L2 merges the 64B pieces into full lines).
__global__ __launch_bounds__(256) void k_gemm(
    const ushort* __restrict__ hT, const ushort* __restrict__ Wfrag,
    const float* __restrict__ bias, float* __restrict__ out)
{
  __shared__ ushort hLds[64][264];         // 528B row stride
  const int bid = blockIdx.x;              // 512 blocks
  const int b   = bid & 7;
  const int n0  = (bid >> 3) * 64;
  const int t    = threadIdx.x;
  const int wave = t >> 6, lane = t & 63;

  {  // stage hT[n0..n0+63][0..255] -> LDS (each thread 128B contiguous)
    const int row  = t >> 2;
    const int coff = (t & 3) * 64;
    const ushort* src = hT + (size_t)b * NN * CC + ((size_t)(n0 + row) << 8) + coff;
    #pragma unroll
    for (int i = 0; i < 8; ++i)
      *(uint4*)&hLds[row][coff + i * 8] = *(const uint4*)(src + i * 8);
  }
  __syncthreads();

  f32x4 acc[4][4];
  #pragma unroll
  for (int m = 0; m < 4; ++m)
    #pragma unroll
    for (int nn = 0; nn < 4; ++nn) acc[m][nn] = (f32x4){0.f, 0.f, 0.f, 0.f};

  const int lrow = lane & 15;
  const int kgrp = lane >> 4;
  const int o0   = wave * 64;

  #pragma unroll
  for (int kc = 0; kc < 8; ++kc) {
    const int cs = kgrp * 8;
    bf16x8 afr[4], bfr[4];
    #pragma unroll
    for (int m = 0; m < 4; ++m) {
      const uint32_t aoff = (uint32_t)(kc * CC + o0 + m * 16 + lrow) * 32 + cs;
      afr[m] = *(const bf16x8*)(Wfrag + aoff);
    }
    #pragma unroll
    for (int nn = 0; nn < 4; ++nn)
      bfr[nn] = *(const bf16x8*)&hLds[nn * 16 + lrow][kc * 32 + cs];
    #pragma unroll
    for (int m = 0; m < 4; ++m)
      #pragma unroll
      for (int nn = 0; nn < 4; ++nn)
        acc[m][nn] = __builtin_amdgcn_mfma_f32_16x16x32_bf16(
            afr[m], bfr[nn], acc[m][nn], 0, 0, 0);
  }

  // Epilogue: D col=lane&15 (n), row=(lane>>4)*4+r (o-local); bias + relu.
  #pragma unroll
  for (int m = 0; m < 4; ++m) {
    const f32x4 bv4 = *(const f32x4*)(bias + o0 + m * 16 + kgrp * 4);
    #pragma unroll
    for (int r = 0; r < 4; ++r) {
      const int o = o0 + m * 16 + kgrp * 4 + r;
      #pragma unroll
      for (int nn = 0; nn < 4; ++nn) {
        const int n = n0 + nn * 16 + lrow;
        float v = acc[m][nn][r] + bv4[r];
        v = v > 0.f ? v : 0.f;
        out[((size_t)b * CC + o) * NN + n] = v;   // plain store: L2 merges
      }
    }
  }
}

extern "C" void kernel_launch(void* const* d_in, const int* in_sizes, int n_in,
                              void* d_out, int out_size, void* d_ws, size_t ws_size,
                              hipStream_t stream) {
  const float* x    = (const float*)d_in[0];
  const int*   edge = (const int*)d_in[1];   // [2][B][N][K] int32, plane 0 used
  const float* eps  = (const float*)d_in[2];
  const float* W    = (const float*)d_in[3];
  const float* bias = (const float*)d_in[4];
  float* out = (float*)d_out;

  ushort* xT    = (ushort*)d_ws;                         // [B][N][C] bf16, 16.8 MB
  ushort* hT    = xT + (size_t)BB * NN * CC;             // [B][N][C] bf16, 16.8 MB
  ushort* Wfrag = hT + (size_t)BB * NN * CC;             // [8][C][32] bf16, 128 KB

  k_prep<<<2048 + 64, 256, 0, stream>>>(x, W, xT, Wfrag);

  k_gather<<<BB * (NN / 16), 256, 0, stream>>>(xT, edge, eps, hT);

  k_gemm<<<BB * (NN / 64), 256, 0, stream>>>(hT, Wfrag, bias, out);
}